// Round 10
// baseline (17811.440 us; speedup 1.0000x reference)
//
#include <hip/hip_runtime.h>
#include <hip/hip_fp16.h>
#include <cstdint>
#include <cstddef>

// ---------------------------------------------------------------------------
// CNN (conv1+pool, conv2+pool) -> seq [256][256][32]
// NTM scan: 128 blocks x 1024 threads, 2 batch/block, 1 block/CU.
// TWO barriers per step:
//  R1: waves 0..11 (768 thr): FULL z-GEMM step i (24 LDS-resident pairs +
//      120 streamed = 480KB);  wave 12: complete NTM chain step i-1, batch 0
//      (P3 coalesced-global head GEMM -> P4 addressing -> P5 read via LDS
//      transpose-reduce -> erase/add), wave 13: same for batch 1.
//  R2: LSTM (3 zparts + WrT*rp reads-term) -> h_i ; x_{i+1} prefetch.
// wprev lives in 4 VGPRs inside the chain wave. M single-buffered (chain
// wave owns all reads+writes, program-order safe). Epilogue: chain(255).
// ci pair slots (u32): [x:0..15][h:16..143], 144 pairs.
// ---------------------------------------------------------------------------

#define MW    20
#define NLOC  128
#define ZC    1024
#define PC    92
#define CLIPV 20.0f

__device__ __forceinline__ float sigmoidf_(float x) { return 1.0f / (1.0f + expf(-x)); }
__device__ __forceinline__ float softplusf_(float x) { return log1pf(expf(x)); }

__device__ __forceinline__ float dot2f(uint32_t w, uint32_t a, float c) {
    asm("v_dot2_f32_f16 %0, %1, %2, %0" : "+v"(c) : "v"(w), "v"(a));
    return c;
}
__device__ __forceinline__ void wave_lds_fence() {
    asm volatile("s_waitcnt lgkmcnt(0)" ::: "memory");
    __builtin_amdgcn_sched_barrier(0);
}

// pair row map (144 pairs): k<32 -> wx row k (x); k in [32,288) -> wh row k-32
__device__ __forceinline__ float wvalA(const float* wx, const float* wh, int k, int col) {
    return (k < 32) ? wx[k * ZC + col] : wh[(k - 32) * ZC + col];
}
__device__ __forceinline__ uint32_t packA(const float* wx, const float* wh, int pr, int col) {
    __half2 h = __floats2half2_rn(wvalA(wx, wh, 2 * pr, col), wvalA(wx, wh, 2 * pr + 1, col));
    return *reinterpret_cast<uint32_t*>(&h);
}

// WG: u32 idx = (pr*256 + c)*4 + m -> col = 4c + m, pr 0..143.
// WrT: [1024 cols][12] u32 (reads pairs q<10: wx rows 32..51), else 0.
// hw2: [128 up][92 col] u32 (coalesced per-lane col reads).
__global__ __launch_bounds__(256) void prep_pack(const float* __restrict__ wx,
                                                 const float* __restrict__ wh,
                                                 const float* __restrict__ hw,
                                                 uint32_t* __restrict__ WG,
                                                 uint32_t* __restrict__ WrT,
                                                 uint32_t* __restrict__ hw2) {
    int idx = blockIdx.x * 256 + threadIdx.x;
    if (idx < 147456) {
        int m = idx & 3, c = (idx >> 2) & 255, pr = idx >> 10;
        WG[idx] = packA(wx, wh, pr, c * 4 + m);
    } else if (idx < 159744) {
        int q2 = idx - 147456;
        int col = q2 / 12, q = q2 - col * 12;
        if (q < 10) {
            __half2 h = __floats2half2_rn(wx[(32 + 2 * q) * ZC + col], wx[(33 + 2 * q) * ZC + col]);
            WrT[q2] = *reinterpret_cast<uint32_t*>(&h);
        } else WrT[q2] = 0u;
    } else if (idx < 171520) {
        int q3 = idx - 159744;
        int up = q3 / 92, col = q3 - up * 92;
        __half2 h = __floats2half2_rn(hw[(2 * up) * PC + col], hw[(2 * up + 1) * PC + col]);
        hw2[q3] = *reinterpret_cast<uint32_t*>(&h);
    }
}

// conv1 3x3 (1->16) SAME + relu + maxpool2
__global__ __launch_bounds__(256) void conv1_pool(const float* __restrict__ in,
                                                  const float* __restrict__ w,
                                                  const float* __restrict__ bias,
                                                  float* __restrict__ out) {
    int idx = blockIdx.x * 256 + threadIdx.x;
    if (idx >= 256 * 32 * 32 * 16) return;
    int c = idx & 15, x = (idx >> 4) & 31, y = (idx >> 9) & 31, b = idx >> 14;
    const float* inb = in + (size_t)b * 4096;
    float bv = bias[c];
    float mx = 0.0f;
    #pragma unroll
    for (int dy = 0; dy < 2; ++dy)
    #pragma unroll
    for (int dx = 0; dx < 2; ++dx) {
        int oy = 2 * y + dy, ox = 2 * x + dx;
        float s = bv;
        #pragma unroll
        for (int ky = 0; ky < 3; ++ky) {
            int iy = oy + ky - 1;
            if (iy < 0 || iy > 63) continue;
            #pragma unroll
            for (int kx = 0; kx < 3; ++kx) {
                int ix = ox + kx - 1;
                if (ix < 0 || ix > 63) continue;
                s = fmaf(inb[iy * 64 + ix], w[(ky * 3 + kx) * 16 + c], s);
            }
        }
        mx = fmaxf(mx, fmaxf(s, 0.0f));
    }
    out[idx] = mx;
}

// conv2 3x3 (16->32) SAME + relu + maxpool2
__global__ __launch_bounds__(256) void conv2_pool(const float* __restrict__ p1,
                                                  const float* __restrict__ w,
                                                  const float* __restrict__ bias,
                                                  float* __restrict__ seq) {
    int idx = blockIdx.x * 256 + threadIdx.x;
    if (idx >= 256 * 16 * 16 * 32) return;
    int c = idx & 31, x = (idx >> 5) & 15, y = (idx >> 9) & 15, b = idx >> 13;
    const float* pb = p1 + (size_t)b * (32 * 32 * 16);
    float bv = bias[c];
    float acc[4] = {bv, bv, bv, bv};
    #pragma unroll
    for (int ky = 0; ky < 3; ++ky)
    #pragma unroll
    for (int kx = 0; kx < 3; ++kx) {
        float w16[16];
        #pragma unroll
        for (int i = 0; i < 16; ++i) w16[i] = w[((ky * 3 + kx) * 16 + i) * 32 + c];
        #pragma unroll
        for (int dy = 0; dy < 2; ++dy)
        #pragma unroll
        for (int dx = 0; dx < 2; ++dx) {
            int iy = 2 * y + dy + ky - 1, ix = 2 * x + dx + kx - 1;
            if (iy < 0 || iy > 31 || ix < 0 || ix > 31) continue;
            const float4* pin4 = (const float4*)(pb + (iy * 32 + ix) * 16);
            float4 v0 = pin4[0], v1 = pin4[1], v2 = pin4[2], v3 = pin4[3];
            int a = dy * 2 + dx;
            acc[a] = fmaf(v0.x, w16[0], acc[a]);  acc[a] = fmaf(v0.y, w16[1], acc[a]);
            acc[a] = fmaf(v0.z, w16[2], acc[a]);  acc[a] = fmaf(v0.w, w16[3], acc[a]);
            acc[a] = fmaf(v1.x, w16[4], acc[a]);  acc[a] = fmaf(v1.y, w16[5], acc[a]);
            acc[a] = fmaf(v1.z, w16[6], acc[a]);  acc[a] = fmaf(v1.w, w16[7], acc[a]);
            acc[a] = fmaf(v2.x, w16[8], acc[a]);  acc[a] = fmaf(v2.y, w16[9], acc[a]);
            acc[a] = fmaf(v2.z, w16[10], acc[a]); acc[a] = fmaf(v2.w, w16[11], acc[a]);
            acc[a] = fmaf(v3.x, w16[12], acc[a]); acc[a] = fmaf(v3.y, w16[13], acc[a]);
            acc[a] = fmaf(v3.z, w16[14], acc[a]); acc[a] = fmaf(v3.w, w16[15], acc[a]);
        }
    }
    float mx = 0.0f;
    #pragma unroll
    for (int a = 0; a < 4; ++a) mx = fmaxf(mx, acc[a]);
    seq[idx] = mx;
}

// ---------------------------------------------------------------------------
// Persistent NTM scan, 2 barriers/step, wave-local NTM chain.
// ---------------------------------------------------------------------------
#define DOT8A(w_, a0_, a1_) \
    a00 = dot2f(w_.x, a0_, a00); a01 = dot2f(w_.y, a0_, a01); \
    a02 = dot2f(w_.z, a0_, a02); a03 = dot2f(w_.w, a0_, a03); \
    a10 = dot2f(w_.x, a1_, a10); a11 = dot2f(w_.y, a1_, a11); \
    a12 = dot2f(w_.z, a1_, a12); a13 = dot2f(w_.w, a1_, a13);

__global__ __launch_bounds__(1024) void ntm_scan10(
    const float* __restrict__ seq,
    const uint32_t* __restrict__ WG,
    const uint32_t* __restrict__ WrT,
    const uint32_t* __restrict__ hw2G,
    const float* __restrict__ lb,
    const float* __restrict__ hb,
    const float* __restrict__ ow,
    const float* __restrict__ ob,
    const float* __restrict__ dw,
    const float* __restrict__ db,
    float* __restrict__ out)          // [256][2]
{
    __shared__ uint4 Wl4[24 * 256];                   // 98304 B (8 pairs per K-third)
    __shared__ float zpart[3][2][ZC];                 // 24576 B
    __shared__ __align__(16) _Float16 ci2h[2][288];   // 1152 B (x pairs 0..15, h 16..143)
    __shared__ float Msh[2][MW][132];                 // 21120 B
    __shared__ float psB[2][PC];                      // 736 B
    __shared__ float evL[2][MW], avL[2][MW];          // 320 B
    __shared__ float pr5[2][32][21];                  // 5376 B
    __shared__ float rds[2][MW];                      // 160 B
    __shared__ uint32_t rp[2][10];                    // 80 B
    __shared__ float o8[2][8];                        // 64 B
    // total ~151.9 KB -> 1 block/CU

    const int t = threadIdx.x;
    const int bs0 = blockIdx.x * 2;
    const int w = t >> 6;
    const uint4* WG4 = (const uint4*)WG;

    // ---- stage resident pairs: per K-third ks2, pairs ks2*48 + 0..7 ----
    for (int i = t; i < 6144; i += 1024) {
        int lp = i >> 8, cc = i & 255;
        int pr = (lp >> 3) * 48 + (lp & 7);
        Wl4[i] = WG4[pr * 256 + cc];
    }

    // ---- init state ----
    for (int i = t; i < 2 * 288; i += 1024) {
        int b = i / 288, k = i - b * 288;
        ci2h[b][k] = (k < 32) ? (_Float16)seq[(size_t)(bs0 + b) * 8192 + k] : (_Float16)0.0f;
    }
    for (int i = t; i < 2 * MW * 132; i += 1024) {
        int b = i / (MW * 132), r = i - b * (MW * 132);
        Msh[b][r / 132][r - (r / 132) * 132] = 1e-6f;
    }
    if (t < 20) {
        __half2 h0 = __floats2half2_rn(1e-6f, 1e-6f);
        rp[t / 10][t % 10] = *reinterpret_cast<uint32_t*>(&h0);
    }
    float c_reg = 0.0f;                // LSTM cell: thread t<512 owns (b=t>>8, u=t&255)
    float wpr0 = 1.0f / 128.0f, wpr1 = 1.0f / 128.0f;
    float wpr2 = 1.0f / 128.0f, wpr3 = 1.0f / 128.0f;   // chain-wave head weights (per lane)
    __syncthreads();

    const uint32_t* ci2u0 = (const uint32_t*)&ci2h[0][0];
    const uint32_t* ci2u1 = (const uint32_t*)&ci2h[1][0];

    // ======= wave-local NTM chain (one wave, one batch, one step) =======
    auto doNTM = [&](int b) {
        const int l = t & 63;
        // ---- P3: head params; lane l -> cols l and l+64 (coalesced) ----
        const uint32_t* hu = (b ? ci2u1 : ci2u0) + 16;
        const int colB = (l < 28) ? (l + 64) : l;
        float sA = 0.0f, sB = 0.0f;
        #pragma unroll 16
        for (int up = 0; up < 128; ++up) {
            uint32_t hv = hu[up];
            sA = dot2f(hw2G[up * 92 + l], hv, sA);
            sB = dot2f(hw2G[up * 92 + colB], hv, sB);
        }
        psB[b][l] = fminf(fmaxf(sA + hb[l], -CLIPV), CLIPV);
        if (l < 28) psB[b][l + 64] = fminf(fmaxf(sB + hb[l + 64], -CLIPV), CLIPV);
        wave_lds_fence();
        if (l < 20) {
            evL[b][l] = sigmoidf_(psB[b][52 + l]);
            avL[b][l] = tanhf(psB[b][72 + l]);
        }
        // ---- P4: addressing; lanes 0..31 head0 (read), 32..63 head1 (write) ----
        const int hh = l >> 5, j = l & 31, base = hh << 5, hc = hh * 26;
        float beta  = softplusf_(psB[b][hc + 20]);
        float gte   = sigmoidf_(psB[b][hc + 21]);
        float s0r = psB[b][hc + 22], s1r = psB[b][hc + 23], s2r = psB[b][hc + 24];
        float mS = fmaxf(s0r, fmaxf(s1r, s2r));
        float q0 = expf(s0r - mS), q1 = expf(s1r - mS), q2 = expf(s2r - mS);
        float qin = 1.0f / (q0 + q1 + q2);
        float sh0 = q0 * qin, sh1 = q1 * qin, sh2 = q2 * qin;
        float gamma = softplusf_(psB[b][hc + 25]) + 1.0f;

        float kvv = (j < 20) ? tanhf(psB[b][hc + j]) : 0.0f;
        float kn2 = kvv * kvv;
        #pragma unroll
        for (int o = 1; o < 32; o <<= 1) kn2 += __shfl_xor(kn2, o, 64);
        float kden = sqrtf(kn2) + 1e-8f;

        float d0 = 0, d1 = 0, d2 = 0, d3 = 0, n0 = 0, n1 = 0, n2 = 0, n3 = 0;
        #pragma unroll
        for (int wi = 0; wi < 20; ++wi) {
            float kk = __shfl(kvv, base + wi, 64);
            float4 mv = *(const float4*)&Msh[b][wi][4 * j];
            d0 = fmaf(kk, mv.x, d0); n0 = fmaf(mv.x, mv.x, n0);
            d1 = fmaf(kk, mv.y, d1); n1 = fmaf(mv.y, mv.y, n1);
            d2 = fmaf(kk, mv.z, d2); n2 = fmaf(mv.z, mv.z, n2);
            d3 = fmaf(kk, mv.w, d3); n3 = fmaf(mv.w, mv.w, n3);
        }
        float x0 = beta * (d0 / ((sqrtf(n0) + 1e-8f) * kden));
        float x1 = beta * (d1 / ((sqrtf(n1) + 1e-8f) * kden));
        float x2 = beta * (d2 / ((sqrtf(n2) + 1e-8f) * kden));
        float x3 = beta * (d3 / ((sqrtf(n3) + 1e-8f) * kden));
        float mx = fmaxf(fmaxf(x0, x1), fmaxf(x2, x3));
        #pragma unroll
        for (int o = 1; o < 32; o <<= 1) mx = fmaxf(mx, __shfl_xor(mx, o, 64));
        float e0 = expf(x0 - mx), e1 = expf(x1 - mx), e2 = expf(x2 - mx), e3 = expf(x3 - mx);
        float se = e0 + e1 + e2 + e3;
        #pragma unroll
        for (int o = 1; o < 32; o <<= 1) se += __shfl_xor(se, o, 64);
        float inv = 1.0f / se;
        float wg0 = gte * (e0 * inv) + (1.0f - gte) * wpr0;
        float wg1 = gte * (e1 * inv) + (1.0f - gte) * wpr1;
        float wg2 = gte * (e2 * inv) + (1.0f - gte) * wpr2;
        float wg3 = gte * (e3 * inv) + (1.0f - gte) * wpr3;
        float wgm = __shfl(wg3, base + ((j + 31) & 31), 64);
        float wgp = __shfl(wg0, base + ((j + 1) & 31), 64);
        float wt0 = sh0 * wg1 + sh1 * wg0 + sh2 * wgm;
        float wt1 = sh0 * wg2 + sh1 * wg1 + sh2 * wg0;
        float wt2 = sh0 * wg3 + sh1 * wg2 + sh2 * wg1;
        float wt3 = sh0 * wgp + sh1 * wg3 + sh2 * wg2;
        float wq0 = expf(gamma * logf(wt0 + 1e-8f));
        float wq1 = expf(gamma * logf(wt1 + 1e-8f));
        float wq2 = expf(gamma * logf(wt2 + 1e-8f));
        float wq3 = expf(gamma * logf(wt3 + 1e-8f));
        float ssum = wq0 + wq1 + wq2 + wq3;
        #pragma unroll
        for (int o = 1; o < 32; o <<= 1) ssum += __shfl_xor(ssum, o, 64);
        float rin = 1.0f / ssum;
        wpr0 = wq0 * rin; wpr1 = wq1 * rin; wpr2 = wq2 * rin; wpr3 = wq3 * rin;

        // ---- P5a: read-head partials (lanes 0..31, OLD M) ----
        if (hh == 0) {
            #pragma unroll
            for (int wi = 0; wi < 20; ++wi) {
                float4 mv = *(const float4*)&Msh[b][wi][4 * j];
                pr5[b][j][wi] = wpr0 * mv.x + wpr1 * mv.y + wpr2 * mv.z + wpr3 * mv.w;
            }
        }
        wave_lds_fence();
        // ---- P5b: erase/add (lanes 32..63, write head) ----
        if (hh == 1) {
            #pragma unroll
            for (int wi = 0; wi < 20; ++wi) {
                float evb = evL[b][wi], avb = avL[b][wi];
                float4 mv = *(const float4*)&Msh[b][wi][4 * j];
                mv.x = mv.x * (1.0f - wpr0 * evb) + wpr0 * avb;
                mv.y = mv.y * (1.0f - wpr1 * evb) + wpr1 * avb;
                mv.z = mv.z * (1.0f - wpr2 * evb) + wpr2 * avb;
                mv.w = mv.w * (1.0f - wpr3 * evb) + wpr3 * avb;
                *(float4*)&Msh[b][wi][4 * j] = mv;
            }
        }
        // ---- P5c: transpose-reduce partials -> r, publish rds/rp ----
        float rv = 0.0f;
        if (l < 20) {
            #pragma unroll
            for (int j2 = 0; j2 < 32; ++j2) rv += pr5[b][j2][l];
            rds[b][l] = rv;
        }
        float ra = __shfl(rv, (2 * l) & 63, 64);
        float rb = __shfl(rv, (2 * l + 1) & 63, 64);
        if (l < 10) {
            __half2 hp = __floats2half2_rn(ra, rb);
            rp[b][l] = *reinterpret_cast<uint32_t*>(&hp);
        }
    };

    const int ks = t >> 8;         // K-third 0..2 (t<768)
    const int c  = t & 255;        // col group 4c..4c+3
    const int prb = ks * 48;

    for (int i = 0; i < 256; ++i) {
        // ================= R1: z-GEMM(step i)  ||  NTM chain(step i-1) =======
        if (t < 768) {
            float a00 = 0, a01 = 0, a02 = 0, a03 = 0;
            float a10 = 0, a11 = 0, a12 = 0, a13 = 0;
            const uint4* cap0 = (const uint4*)(ci2u0 + prb);
            const uint4* cap1 = (const uint4*)(ci2u1 + prb);
            #pragma unroll
            for (int g = 0; g < 12; ++g) {
                uint4 A = cap0[g];
                uint4 Bv = cap1[g];
                uint32_t aa[4] = {A.x, A.y, A.z, A.w};
                uint32_t bb[4] = {Bv.x, Bv.y, Bv.z, Bv.w};
                #pragma unroll
                for (int q = 0; q < 4; ++q) {
                    const int p = 4 * g + q;
                    uint4 wq = (p < 8) ? Wl4[(ks * 8 + p) * 256 + c]
                                       : WG4[(prb + p) * 256 + c];
                    DOT8A(wq, aa[q], bb[q])
                }
            }
            *(float4*)&zpart[ks][0][4 * c] = make_float4(a00, a01, a02, a03);
            *(float4*)&zpart[ks][1][4 * c] = make_float4(a10, a11, a12, a13);
        } else if (w == 12) {
            if (i > 0) doNTM(0);
        } else if (w == 13) {
            if (i > 0) doNTM(1);
        }
        __syncthreads();   // B1

        // ================= R2: LSTM step i + x prefetch =================
        if (t < 512) {
            int b = t >> 8, u = t & 255;
            uint32_t rp0 = rp[b][0], rp1 = rp[b][1], rp2 = rp[b][2], rp3 = rp[b][3];
            uint32_t rp4 = rp[b][4], rp5 = rp[b][5], rp6 = rp[b][6], rp7 = rp[b][7];
            uint32_t rp8 = rp[b][8], rp9 = rp[b][9];
            float zg4[4];
            #pragma unroll
            for (int g4 = 0; g4 < 4; ++g4) {
                const uint4* wp = (const uint4*)(WrT + ((g4 << 8) + u) * 12);
                uint4 A = wp[0], B = wp[1], C = wp[2];
                float s = 0.0f;
                s = dot2f(A.x, rp0, s); s = dot2f(A.y, rp1, s);
                s = dot2f(A.z, rp2, s); s = dot2f(A.w, rp3, s);
                s = dot2f(B.x, rp4, s); s = dot2f(B.y, rp5, s);
                s = dot2f(B.z, rp6, s); s = dot2f(B.w, rp7, s);
                s = dot2f(C.x, rp8, s); s = dot2f(C.y, rp9, s);
                zg4[g4] = s;
            }
            float zi = lb[u]       + zg4[0] + zpart[0][b][u]       + zpart[1][b][u]       + zpart[2][b][u];
            float zf = lb[256 + u] + zg4[1] + zpart[0][b][256 + u] + zpart[1][b][256 + u] + zpart[2][b][256 + u];
            float zg = lb[512 + u] + zg4[2] + zpart[0][b][512 + u] + zpart[1][b][512 + u] + zpart[2][b][512 + u];
            float zo = lb[768 + u] + zg4[3] + zpart[0][b][768 + u] + zpart[1][b][768 + u] + zpart[2][b][768 + u];
            float cg = sigmoidf_(zf) * c_reg + sigmoidf_(zi) * tanhf(zg);
            c_reg = cg;
            ci2h[b][32 + u] = (_Float16)(sigmoidf_(zo) * tanhf(cg));
        } else if (t >= 896 && t < 960 && i < 255) {
            int q = t - 896, b = q >> 5, cc = q & 31;
            ci2h[b][cc] = (_Float16)seq[(size_t)(bs0 + b) * 8192 + (size_t)(i + 1) * 32 + cc];
        }
        __syncthreads();   // B2
    }

    // ---- epilogue: NTM chain for step 255 (produces reads_255 -> rds) ----
    if (w == 12) doNTM(0);
    else if (w == 13) doNTM(1);
    __syncthreads();

    // ---- final NTM output head + dense + softmax ----
    if (t < 16) {
        int b = t >> 3, o = t & 7;
        float s = ob[o];
        for (int u = 0; u < 256; ++u) s = fmaf((float)ci2h[b][32 + u], ow[u * 8 + o], s);
        #pragma unroll
        for (int wi = 0; wi < 20; ++wi) s = fmaf(rds[b][wi], ow[(256 + wi) * 8 + o], s);
        o8[b][o] = fminf(fmaxf(s, -CLIPV), CLIPV);
    }
    __syncthreads();
    if (t < 2) {
        float l0 = db[0], l1 = db[1];
        #pragma unroll
        for (int k = 0; k < 8; ++k) {
            float v = o8[t][k];
            l0 = fmaf(v, dw[k * 2 + 0], l0);
            l1 = fmaf(v, dw[k * 2 + 1], l1);
        }
        float m = fmaxf(l0, l1);
        float q0 = expf(l0 - m), q1 = expf(l1 - m);
        float inv = 1.0f / (q0 + q1);
        out[(bs0 + t) * 2 + 0] = q0 * inv;
        out[(bs0 + t) * 2 + 1] = q1 * inv;
    }
}

extern "C" void kernel_launch(void* const* d_in, const int* in_sizes, int n_in,
                              void* d_out, int out_size, void* d_ws, size_t ws_size,
                              hipStream_t stream) {
    const float* inputs = (const float*)d_in[0];
    const float* c1w = (const float*)d_in[1];
    const float* c1b = (const float*)d_in[2];
    const float* c2w = (const float*)d_in[3];
    const float* c2b = (const float*)d_in[4];
    const float* lwx = (const float*)d_in[5];
    const float* lwh = (const float*)d_in[6];
    const float* lb  = (const float*)d_in[7];
    const float* hw  = (const float*)d_in[8];
    const float* hb  = (const float*)d_in[9];
    const float* ow  = (const float*)d_in[10];
    const float* ob  = (const float*)d_in[11];
    const float* dw  = (const float*)d_in[12];
    const float* db  = (const float*)d_in[13];
    float* out = (float*)d_out;

    float* ws  = (float*)d_ws;
    float* p1  = ws;                             // 4,194,304 f
    float* seq = ws + 4194304;                   // 2,097,152 f
    uint32_t* WG   = (uint32_t*)(ws + 6291456);  // 147,456 u32
    uint32_t* WrT  = WG + 147456;                //  12,288 u32
    uint32_t* hw2G = WrT + 12288;                //  11,776 u32

    hipLaunchKernelGGL(prep_pack,  dim3(670),   dim3(256),  0, stream, lwx, lwh, hw, WG, WrT, hw2G);
    hipLaunchKernelGGL(conv1_pool, dim3(16384), dim3(256),  0, stream, inputs, c1w, c1b, p1);
    hipLaunchKernelGGL(conv2_pool, dim3(8192),  dim3(256),  0, stream, p1, c2w, c2b, seq);
    hipLaunchKernelGGL(ntm_scan10, dim3(128),   dim3(1024), 0, stream,
                       seq, WG, WrT, hw2G, lb, hb, ow, ob, dw, db, out);
}

// Round 11
// 3104.321 us; speedup vs baseline: 5.7376x; 5.7376x over previous
//
#include <hip/hip_runtime.h>
#include <hip/hip_fp16.h>
#include <cstdint>
#include <cstddef>

// ---------------------------------------------------------------------------
// CNN (conv1+pool, conv2+pool) -> seq [256][256][32]
// NTM scan: 256 blocks x 1024 threads, 1 batch/block, 1 block/CU.
// R5's proven phase structure (5 barriers) at 2x thread density per batch:
//   P1 z-GEMM (160 pairs: 32 LDS-resident, 128 streamed = 512KB/step)
//   P2 LSTM (+ x prefetch) | P3 head GEMM 4-way | P4 addressing (2 waves)
//   P5 fused read + erase/add.
// No register weight caching, no bulk state across barriers (R3/R4/R8/R10).
// ci slots (fp16 halves): x 0..31, reads 32..51, h 52..307, pad ->320.
// ---------------------------------------------------------------------------

#define MW    20
#define NLOC  128
#define ZC    1024
#define PC    92
#define CLIPV 20.0f

__device__ __forceinline__ float sigmoidf_(float x) { return 1.0f / (1.0f + expf(-x)); }
__device__ __forceinline__ float softplusf_(float x) { return log1pf(expf(x)); }

__device__ __forceinline__ float dot2f(uint32_t w, uint32_t a, float c) {
    asm("v_dot2_f32_f16 %0, %1, %2, %0" : "+v"(c) : "v"(w), "v"(a));
    return c;
}

// K pairs pr = k/2 (K 308 -> 320 pad, 160 pairs):
//   k 0..31 xt, 32..51 reads, 52..307 h, 308..319 zero pad.
__device__ __forceinline__ float wval(const float* wx, const float* wh, int k, int col) {
    if (k < 52)  return wx[k * ZC + col];
    if (k < 308) return wh[(k - 52) * ZC + col];
    return 0.0f;
}
__device__ __forceinline__ uint32_t packpr(const float* wx, const float* wh, int pr, int col) {
    __half2 h = __floats2half2_rn(wval(wx, wh, 2 * pr, col), wval(wx, wh, 2 * pr + 1, col));
    return *reinterpret_cast<uint32_t*>(&h);
}

// WG layout: u32 idx = (pair*256 + c)*4 + m  -> col = 4c + m.
__global__ __launch_bounds__(256) void prep_pack(const float* __restrict__ wx,
                                                 const float* __restrict__ wh,
                                                 const float* __restrict__ hw,
                                                 uint32_t* __restrict__ WG,     // [160][256][4]
                                                 uint32_t* __restrict__ hw2G) { // [128][92]
    int idx = blockIdx.x * 256 + threadIdx.x;
    if (idx < 163840) {
        int m = idx & 3, cc = (idx >> 2) & 255, pair = idx >> 10;
        WG[idx] = packpr(wx, wh, pair, cc * 4 + m);
    } else if (idx < 163840 + 11776) {
        int q = idx - 163840;
        int up = q / 92, col = q - up * 92;
        __half2 h = __floats2half2_rn(hw[(2 * up) * PC + col], hw[(2 * up + 1) * PC + col]);
        hw2G[q] = *reinterpret_cast<uint32_t*>(&h);
    }
}

// conv1 3x3 (1->16) SAME + relu + maxpool2
__global__ __launch_bounds__(256) void conv1_pool(const float* __restrict__ in,
                                                  const float* __restrict__ w,
                                                  const float* __restrict__ bias,
                                                  float* __restrict__ out) {
    int idx = blockIdx.x * 256 + threadIdx.x;
    if (idx >= 256 * 32 * 32 * 16) return;
    int c = idx & 15, x = (idx >> 4) & 31, y = (idx >> 9) & 31, b = idx >> 14;
    const float* inb = in + (size_t)b * 4096;
    float bv = bias[c];
    float mx = 0.0f;
    #pragma unroll
    for (int dy = 0; dy < 2; ++dy)
    #pragma unroll
    for (int dx = 0; dx < 2; ++dx) {
        int oy = 2 * y + dy, ox = 2 * x + dx;
        float s = bv;
        #pragma unroll
        for (int ky = 0; ky < 3; ++ky) {
            int iy = oy + ky - 1;
            if (iy < 0 || iy > 63) continue;
            #pragma unroll
            for (int kx = 0; kx < 3; ++kx) {
                int ix = ox + kx - 1;
                if (ix < 0 || ix > 63) continue;
                s = fmaf(inb[iy * 64 + ix], w[(ky * 3 + kx) * 16 + c], s);
            }
        }
        mx = fmaxf(mx, fmaxf(s, 0.0f));
    }
    out[idx] = mx;
}

// conv2 3x3 (16->32) SAME + relu + maxpool2 (weights hoisted per tap, f4 inputs)
__global__ __launch_bounds__(256) void conv2_pool(const float* __restrict__ p1,
                                                  const float* __restrict__ w,
                                                  const float* __restrict__ bias,
                                                  float* __restrict__ seq) {
    int idx = blockIdx.x * 256 + threadIdx.x;
    if (idx >= 256 * 16 * 16 * 32) return;
    int c = idx & 31, x = (idx >> 5) & 15, y = (idx >> 9) & 15, b = idx >> 13;
    const float* pb = p1 + (size_t)b * (32 * 32 * 16);
    float bv = bias[c];
    float acc[4] = {bv, bv, bv, bv};
    #pragma unroll
    for (int ky = 0; ky < 3; ++ky)
    #pragma unroll
    for (int kx = 0; kx < 3; ++kx) {
        float w16[16];
        #pragma unroll
        for (int i = 0; i < 16; ++i) w16[i] = w[((ky * 3 + kx) * 16 + i) * 32 + c];
        #pragma unroll
        for (int dy = 0; dy < 2; ++dy)
        #pragma unroll
        for (int dx = 0; dx < 2; ++dx) {
            int iy = 2 * y + dy + ky - 1, ix = 2 * x + dx + kx - 1;
            if (iy < 0 || iy > 31 || ix < 0 || ix > 31) continue;
            const float4* pin4 = (const float4*)(pb + (iy * 32 + ix) * 16);
            float4 v0 = pin4[0], v1 = pin4[1], v2 = pin4[2], v3 = pin4[3];
            int a = dy * 2 + dx;
            acc[a] = fmaf(v0.x, w16[0], acc[a]);  acc[a] = fmaf(v0.y, w16[1], acc[a]);
            acc[a] = fmaf(v0.z, w16[2], acc[a]);  acc[a] = fmaf(v0.w, w16[3], acc[a]);
            acc[a] = fmaf(v1.x, w16[4], acc[a]);  acc[a] = fmaf(v1.y, w16[5], acc[a]);
            acc[a] = fmaf(v1.z, w16[6], acc[a]);  acc[a] = fmaf(v1.w, w16[7], acc[a]);
            acc[a] = fmaf(v2.x, w16[8], acc[a]);  acc[a] = fmaf(v2.y, w16[9], acc[a]);
            acc[a] = fmaf(v2.z, w16[10], acc[a]); acc[a] = fmaf(v2.w, w16[11], acc[a]);
            acc[a] = fmaf(v3.x, w16[12], acc[a]); acc[a] = fmaf(v3.y, w16[13], acc[a]);
            acc[a] = fmaf(v3.z, w16[14], acc[a]); acc[a] = fmaf(v3.w, w16[15], acc[a]);
        }
    }
    float mx = 0.0f;
    #pragma unroll
    for (int a = 0; a < 4; ++a) mx = fmaxf(mx, acc[a]);
    seq[idx] = mx;
}

// ---------------------------------------------------------------------------
// Persistent NTM scan: 1 batch/block, 1024 threads, 5 barriers/step.
// ---------------------------------------------------------------------------
#define PSCLIP1(col_) fminf(fmaxf(pp[0][col_] + pp[1][col_] + pp[2][col_] + pp[3][col_] + hb[col_], -CLIPV), CLIPV)

__global__ __launch_bounds__(1024, 4) void ntm_scan11(
    const float* __restrict__ seq,
    const uint32_t* __restrict__ WG,
    const uint32_t* __restrict__ hw2G,
    const float* __restrict__ lb,
    const float* __restrict__ hb,
    const float* __restrict__ ow,
    const float* __restrict__ ob,
    const float* __restrict__ dw,
    const float* __restrict__ db,
    float* __restrict__ out)          // [256][2]
{
    __shared__ uint4 Wl4[32 * 256];                   // 131072 B (8 pairs per K-quarter)
    __shared__ float zpart[4][ZC];                    // 16384 B
    __shared__ __align__(16) _Float16 ci2h[320];      // 640 B
    __shared__ float Msh[MW][132];                    // 10560 B
    __shared__ float wprev[2][NLOC];                  // 1024 B
    __shared__ float pp[4][PC];                       // 1472 B
    __shared__ float evs[MW], avs[MW];                // 160 B
    __shared__ float rds[MW];                         // 80 B
    __shared__ float o8[8];                           // 32 B
    // total ~158.6 KB -> 1 block/CU

    const int t = threadIdx.x;
    const int bb = blockIdx.x;
    const int kq = t >> 8, c = t & 255;
    const int prb = kq * 40;
    const uint4* WG4 = (const uint4*)WG;

    // ---- stage LDS-resident pairs: per quarter, pairs 0..7 ----
    for (int i = t; i < 8192; i += 1024) {
        int lp = i >> 8, cc = i & 255;
        int pr = (lp >> 3) * 40 + (lp & 7);
        Wl4[i] = WG4[pr * 256 + cc];
    }

    // ---- init state ----
    for (int i = t; i < 320; i += 1024) {
        _Float16 v;
        if (i < 32)      v = (_Float16)seq[(size_t)bb * 8192 + i];
        else if (i < 52) v = (_Float16)1e-6f;
        else             v = (_Float16)0.0f;
        ci2h[i] = v;
    }
    for (int i = t; i < MW * 132; i += 1024)
        Msh[i / 132][i - (i / 132) * 132] = 1e-6f;
    if (t < 256) wprev[t >> 7][t & 127] = 1.0f / 128.0f;
    float c_reg = 0.0f;   // cell state: thread t<256 owns u=t
    __syncthreads();

    const uint32_t* ci2u = (const uint32_t*)&ci2h[0];

    for (int step = 0; step < 256; ++step) {
        // ---- P1: z = ci @ [Wx;Wh] via dot2; kq K-quarter, cols 4c..4c+3 ----
        {
            float a0 = 0.f, a1 = 0.f, a2 = 0.f, a3 = 0.f;
            const uint4* cap = (const uint4*)(ci2u + prb);
            #pragma unroll
            for (int cc2 = 0; cc2 < 10; ++cc2) {
                uint4 a4 = cap[cc2];
                uint32_t aa[4] = {a4.x, a4.y, a4.z, a4.w};
                #pragma unroll
                for (int q = 0; q < 4; ++q) {
                    const int p = cc2 * 4 + q;
                    uint4 w = (p < 8) ? Wl4[(kq * 8 + p) * 256 + c]
                                      : WG4[(prb + p) * 256 + c];
                    a0 = dot2f(w.x, aa[q], a0);
                    a1 = dot2f(w.y, aa[q], a1);
                    a2 = dot2f(w.z, aa[q], a2);
                    a3 = dot2f(w.w, aa[q], a3);
                }
            }
            *reinterpret_cast<float4*>(&zpart[kq][4 * c]) = make_float4(a0, a1, a2, a3);
        }
        __syncthreads();   // B1

        // ---- P2: LSTM update (+ next-xt prefetch on high threads) ----
        if (t < 256) {
            float zi = lb[t], zf = lb[256 + t], zg = lb[512 + t], zo = lb[768 + t];
            #pragma unroll
            for (int q = 0; q < 4; ++q) {
                zi += zpart[q][t];       zf += zpart[q][256 + t];
                zg += zpart[q][512 + t]; zo += zpart[q][768 + t];
            }
            float cg = sigmoidf_(zf) * c_reg + sigmoidf_(zi) * tanhf(zg);
            c_reg = cg;
            ci2h[52 + t] = (_Float16)(sigmoidf_(zo) * tanhf(cg));
        } else if (t >= 768 && t < 800 && step < 255) {
            int cc = t - 768;
            ci2h[cc] = (_Float16)seq[(size_t)bb * 8192 + (size_t)(step + 1) * 32 + cc];
        }
        __syncthreads();   // B2

        // ---- P3: head-param GEMM partials via dot2 (4-way u split) ----
        if (t < 368) {
            int kq2 = t / 92, col = t - kq2 * 92;
            const uint32_t* hwp = hw2G + kq2 * 32 * 92 + col;
            const uint32_t* hbp = ci2u + 26 + kq2 * 32;
            float s = 0.0f;
            #pragma unroll 8
            for (int uu = 0; uu < 32; ++uu)
                s = dot2f(hwp[uu * 92], hbp[uu], s);
            pp[kq2][col] = s;
        }
        __syncthreads();   // B3

        // ---- P4: addressing (2 waves, one per head); evs/avs on 128..167 ----
        if (t < 128) {
            const int l = t & 63, hh = t >> 6;
            const int hc = hh * 26;
            float beta  = softplusf_(PSCLIP1(hc + 20));
            float g     = sigmoidf_(PSCLIP1(hc + 21));
            float s0r = PSCLIP1(hc + 22), s1r = PSCLIP1(hc + 23), s2r = PSCLIP1(hc + 24);
            float mS = fmaxf(s0r, fmaxf(s1r, s2r));
            float q0 = expf(s0r - mS), q1 = expf(s1r - mS), q2 = expf(s2r - mS);
            float qin = 1.0f / (q0 + q1 + q2);
            float sh0 = q0 * qin, sh1 = q1 * qin, sh2 = q2 * qin;
            float gamma = softplusf_(PSCLIP1(hc + 25)) + 1.0f;

            float kvv = (l < 20) ? tanhf(PSCLIP1(hc + l)) : 0.0f;
            float kn2 = kvv * kvv;
            #pragma unroll
            for (int o = 1; o < 64; o <<= 1) kn2 += __shfl_xor(kn2, o, 64);
            float kden = sqrtf(kn2) + 1e-8f;

            float d0 = 0, d1 = 0, m20 = 0, m21 = 0;
            #pragma unroll
            for (int wi = 0; wi < 20; ++wi) {
                float kk = __shfl(kvv, wi, 64);
                float2 mv = *reinterpret_cast<const float2*>(&Msh[wi][2 * l]);
                d0  = fmaf(kk, mv.x, d0);      d1  = fmaf(kk, mv.y, d1);
                m20 = fmaf(mv.x, mv.x, m20);   m21 = fmaf(mv.y, mv.y, m21);
            }
            float x0 = beta * (d0 / ((sqrtf(m20) + 1e-8f) * kden));
            float x1 = beta * (d1 / ((sqrtf(m21) + 1e-8f) * kden));
            float mx = fmaxf(x0, x1);
            #pragma unroll
            for (int o = 1; o < 64; o <<= 1) mx = fmaxf(mx, __shfl_xor(mx, o, 64));
            float e0 = expf(x0 - mx), e1 = expf(x1 - mx);
            float se = e0 + e1;
            #pragma unroll
            for (int o = 1; o < 64; o <<= 1) se += __shfl_xor(se, o, 64);
            float inv = 1.0f / se;
            float2 wpv = *reinterpret_cast<const float2*>(&wprev[hh][2 * l]);
            float wg0 = g * (e0 * inv) + (1.0f - g) * wpv.x;
            float wg1 = g * (e1 * inv) + (1.0f - g) * wpv.y;
            float wgm = __shfl(wg1, (l + 63) & 63, 64);
            float wgp = __shfl(wg0, (l + 1) & 63, 64);
            float wt0 = sh0 * wg1 + sh1 * wg0 + sh2 * wgm;
            float wt1 = sh0 * wgp + sh1 * wg1 + sh2 * wg0;
            float wpw0 = expf(gamma * logf(wt0 + 1e-8f));
            float wpw1 = expf(gamma * logf(wt1 + 1e-8f));
            float ssum = wpw0 + wpw1;
            #pragma unroll
            for (int o = 1; o < 64; o <<= 1) ssum += __shfl_xor(ssum, o, 64);
            float rin = 1.0f / ssum;
            *reinterpret_cast<float2*>(&wprev[hh][2 * l]) = make_float2(wpw0 * rin, wpw1 * rin);
        } else if (t < 168) {
            int r2 = t - 128;
            if (r2 < 20) evs[r2]      = sigmoidf_(PSCLIP1(52 + r2));
            else         avs[r2 - 20] = tanhf(PSCLIP1(72 + (r2 - 20)));
        }
        __syncthreads();   // B4

        // ---- P5: fused read-dot + erase/add (each M element touched once) ----
        if (t < 320) {
            int wi = t >> 4, l16 = t & 15;
            int n0 = l16 * 8;
            float ev = evs[wi], av = avs[wi];
            float s = 0.0f;
            #pragma unroll
            for (int n = n0; n < n0 + 8; ++n) {
                float mv = Msh[wi][n];
                s = fmaf(wprev[0][n], mv, s);
                float wwn = wprev[1][n];
                Msh[wi][n] = mv * (1.0f - wwn * ev) + wwn * av;
            }
            s += __shfl_xor(s, 1, 64); s += __shfl_xor(s, 2, 64);
            s += __shfl_xor(s, 4, 64); s += __shfl_xor(s, 8, 64);
            if (l16 == 0) { rds[wi] = s; ci2h[32 + wi] = (_Float16)s; }
        }
        __syncthreads();   // B5
    }

    // ---- final NTM output head + dense + softmax ----
    if (t < 8) {
        float s = ob[t];
        for (int u = 0; u < 256; ++u) s = fmaf((float)ci2h[52 + u], ow[u * 8 + t], s);
        #pragma unroll
        for (int wi = 0; wi < 20; ++wi) s = fmaf(rds[wi], ow[(256 + wi) * 8 + t], s);
        o8[t] = fminf(fmaxf(s, -CLIPV), CLIPV);
    }
    __syncthreads();
    if (t == 0) {
        float l0 = db[0], l1 = db[1];
        #pragma unroll
        for (int k = 0; k < 8; ++k) {
            float v = o8[k];
            l0 = fmaf(v, dw[k * 2 + 0], l0);
            l1 = fmaf(v, dw[k * 2 + 1], l1);
        }
        float m = fmaxf(l0, l1);
        float q0 = expf(l0 - m), q1 = expf(l1 - m);
        float inv = 1.0f / (q0 + q1);
        out[bb * 2 + 0] = q0 * inv;
        out[bb * 2 + 1] = q1 * inv;
    }
}

extern "C" void kernel_launch(void* const* d_in, const int* in_sizes, int n_in,
                              void* d_out, int out_size, void* d_ws, size_t ws_size,
                              hipStream_t stream) {
    const float* inputs = (const float*)d_in[0];
    const float* c1w = (const float*)d_in[1];
    const float* c1b = (const float*)d_in[2];
    const float* c2w = (const float*)d_in[3];
    const float* c2b = (const float*)d_in[4];
    const float* lwx = (const float*)d_in[5];
    const float* lwh = (const float*)d_in[6];
    const float* lb  = (const float*)d_in[7];
    const float* hw  = (const float*)d_in[8];
    const float* hb  = (const float*)d_in[9];
    const float* ow  = (const float*)d_in[10];
    const float* ob  = (const float*)d_in[11];
    const float* dw  = (const float*)d_in[12];
    const float* db  = (const float*)d_in[13];
    float* out = (float*)d_out;

    float* ws  = (float*)d_ws;
    float* p1  = ws;                             // 4,194,304 f
    float* seq = ws + 4194304;                   // 2,097,152 f
    uint32_t* WG   = (uint32_t*)(ws + 6291456);  // 163,840 u32
    uint32_t* hw2G = WG + 163840;                //  11,776 u32

    hipLaunchKernelGGL(prep_pack,   dim3(686),   dim3(256),  0, stream, lwx, lwh, hw, WG, hw2G);
    hipLaunchKernelGGL(conv1_pool,  dim3(16384), dim3(256),  0, stream, inputs, c1w, c1b, p1);
    hipLaunchKernelGGL(conv2_pool,  dim3(8192),  dim3(256),  0, stream, p1, c2w, c2b, seq);
    hipLaunchKernelGGL(ntm_scan11,  dim3(256),   dim3(1024), 0, stream,
                       seq, WG, hw2G, lb, hb, ow, ob, dw, db, out);
}